// Round 17
// baseline (174.577 us; speedup 1.0000x reference)
//
#include <hip/hip_runtime.h>
#include <hip/hip_bf16.h>
#include <math.h>

constexpr int B_  = 16;
constexpr int C_  = 1536;
constexpr int T_  = 2000;
constexpr int H_  = 128;
constexpr int C3_ = 3 * C_;   // 4608
constexpr int C2_ = 2 * C_;   // 3072
constexpr int NT_ = 4;        // t-parts for gemm2 (512 t each)
constexpr float LOG2E_ = 1.44269504088896340736f;

typedef short bf8 __attribute__((ext_vector_type(8)));   // 8 bf16 (4 VGPR) MFMA A/B frag
typedef short bf4 __attribute__((ext_vector_type(4)));   // 4 bf16 (8B)
typedef float f4  __attribute__((ext_vector_type(4)));   // MFMA C/D frag

// fp32 -> bf16 RTNE (hardware cvt; compiler pairs into v_cvt_pk_bf16_f32)
__device__ inline unsigned short f2b(float f) {
  __bf16 h = (__bf16)f;
  return __builtin_bit_cast(unsigned short, h);
}
// bf16 bits -> fp32 (exact)
__device__ inline float b2f(unsigned short u) {
  return __builtin_bit_cast(float, (unsigned int)u << 16);
}

// ---------------- K1: masked stats over T + bf16 conversion (one wave/row) ----
// Reads x once: computes mean0/std0 AND writes xb = bf16(x) (same layout).
// xb feeds gemm1's B-operand (bit-identical to its previous in-kernel cvt)
// and gemm2's pooling loads (halves both passes' x bytes).
__global__ __launch_bounds__(256) void k_stats_cvt(
    const float* __restrict__ x, const float* __restrict__ mask,
    float* __restrict__ mean0, float* __restrict__ std0,
    unsigned short* __restrict__ xb) {
  const int wave = threadIdx.x >> 6;
  const int lane = threadIdx.x & 63;
  const int row = blockIdx.x * 4 + wave;      // b*C + c
  const int b = row / C_;
  const float4* xr = (const float4*)(x + (size_t)row * T_);
  const float4* mr = (const float4*)(mask + (size_t)b * T_);
  unsigned short* xbr = xb + (size_t)row * T_;
  float sm = 0.f, s1 = 0.f, s2 = 0.f;
  for (int i = lane; i < T_ / 4; i += 64) {
    float4 xv = xr[i];
    float4 mv = mr[i];
    sm += mv.x + mv.y + mv.z + mv.w;
    s1 += mv.x * xv.x + mv.y * xv.y + mv.z * xv.z + mv.w * xv.w;
    s2 += mv.x * xv.x * xv.x + mv.y * xv.y * xv.y + mv.z * xv.z * xv.z + mv.w * xv.w * xv.w;
    bf4 p;
    p[0] = (short)f2b(xv.x); p[1] = (short)f2b(xv.y);
    p[2] = (short)f2b(xv.z); p[3] = (short)f2b(xv.w);
    *(bf4*)&xbr[i * 4] = p;
  }
#pragma unroll
  for (int off = 32; off; off >>= 1) {
    sm += __shfl_xor(sm, off);
    s1 += __shfl_xor(s1, off);
    s2 += __shfl_xor(s2, off);
  }
  if (lane == 0) {
    float mean = s1 / sm;
    float var = s2 / sm - mean * mean;
    mean0[row] = mean;
    std0[row] = sqrtf(fmaxf(var, 1e-5f));
  }
}

// ---------------- K2: hconst GEMV + wl1 L1-norms in ONE launch ----------------
// wl1 is pre-scaled by log2(e) to match gemm2's log2-domain logits.
__global__ __launch_bounds__(256) void k_hconst_wl1(
    const float* __restrict__ w1, const float* __restrict__ b1,
    const float* __restrict__ mean0, const float* __restrict__ std0,
    const float* __restrict__ w2,
    float* __restrict__ hconst, float* __restrict__ wl1) {
  const int wave = threadIdx.x >> 6;
  const int lane = threadIdx.x & 63;
  if (blockIdx.x < B_ * H_ / 4) {
    const int idx = blockIdx.x * 4 + wave;      // b*H + h
    const int b = idx >> 7;
    const int h = idx & (H_ - 1);
    const float* wm  = w1 + (size_t)h * C3_ + C_;
    const float* wsd = wm + C_;
    const float* mn = mean0 + b * C_;
    const float* sd = std0 + b * C_;
    float s = 0.f;
    for (int c = lane; c < C_; c += 64)
      s += wm[c] * mn[c] + wsd[c] * sd[c];
#pragma unroll
    for (int off = 32; off; off >>= 1) s += __shfl_xor(s, off);
    if (lane == 0) hconst[idx] = s + b1[h];
  } else {
    const int c = (blockIdx.x - B_ * H_ / 4) * 4 + wave;
    const float* wr = w2 + (size_t)c * H_;
    float s = fabsf(wr[lane]) + fabsf(wr[lane + 64]);
#pragma unroll
    for (int off = 32; off; off >>= 1) s += __shfl_xor(s, off);
    if (lane == 0) wl1[c] = s * LOG2E_;
  }
}

// ---------------- K3: MFMA GEMM1 (reg-B from xb) + relu/LN/tanh -> hlnT -------
// block 256 thr (4 waves), tile 128h x 64t; wave w owns t-slice w*16..+15.
// B-operand: 8 scalar u16 loads of bf16 xb (half the bytes of R16's fp32
// loads, zero conversion VALU). A (w1) in LDS, conflict-free.
__global__ __launch_bounds__(256) void k_gemm1_ln(
    const unsigned short* __restrict__ xb, const float* __restrict__ w1,
    const float* __restrict__ hconst, const float* __restrict__ g1,
    const float* __restrict__ be1, unsigned short* __restrict__ hlnT) {
  __shared__ __align__(16) short As[2][128 * 32];
  const int b = blockIdx.y;
  const int t0 = blockIdx.x * 64;
  const int tid = threadIdx.x;
  const int lane = tid & 63;
  const int w = tid >> 6;
  const int l15 = lane & 15;
  const int l4 = lane >> 4;
  // this lane's t-column (clamped; t>=T_ columns produce garbage that is
  // never stored -- LN is per t-column so no contamination)
  const int tcl = min(t0 + w * 16 + l15, T_ - 1);
  const unsigned short* xcol = xb + (size_t)b * C_ * T_ + tcl;

  float4 va[4];
  unsigned short xs0[8], xs1[8];

  f4 acc[8];
#pragma unroll
  for (int mi = 0; mi < 8; ++mi) { f4 z = {0.f, 0.f, 0.f, 0.f}; acc[mi] = z; }

#define G1_GLOADA(K0)                                                         \
  {                                                                           \
    _Pragma("unroll")                                                         \
    for (int q = 0; q < 4; ++q) {                                             \
      int idx = q * 256 + tid;                                                \
      int row = idx >> 3, j4 = idx & 7;                                       \
      va[q] = *(const float4*)(w1 + (size_t)row * C3_ + (K0) + j4 * 4);       \
    }                                                                         \
  }
#define G1_GLOADB(K0, XS)                                                     \
  {                                                                           \
    const unsigned short* xq = xcol + ((size_t)(K0) + l4 * 8) * T_;           \
    _Pragma("unroll")                                                         \
    for (int j = 0; j < 8; ++j) XS[j] = xq[(size_t)j * T_];                   \
  }
#define G1_LSTOREA(BUF)                                                       \
  {                                                                           \
    _Pragma("unroll")                                                         \
    for (int q = 0; q < 4; ++q) {                                             \
      int idx = q * 256 + tid;                                                \
      int row = idx >> 3, j4 = idx & 7;                                       \
      int slot = (j4 >> 1) ^ ((row >> 2) & 3);                                \
      bf4 p;                                                                  \
      p[0] = (short)f2b(va[q].x); p[1] = (short)f2b(va[q].y);                 \
      p[2] = (short)f2b(va[q].z); p[3] = (short)f2b(va[q].w);                 \
      *(bf4*)&As[BUF][row * 32 + slot * 8 + (j4 & 1) * 4] = p;                \
    }                                                                         \
  }
// one K-step: prefetch A+B for step s+1, compute step s from regs+LDS[CUR]
#define G1_STEP(S, XSCUR, XSNXT, CUR)                                         \
  {                                                                           \
    if ((S) + 1 < NS) {                                                       \
      G1_GLOADA(((S) + 1) * 32);                                              \
      G1_GLOADB(((S) + 1) * 32, XSNXT);                                       \
    }                                                                         \
    bf8 bfr;                                                                  \
    _Pragma("unroll")                                                         \
    for (int j = 0; j < 8; ++j) bfr[j] = (short)XSCUR[j];                     \
    _Pragma("unroll")                                                         \
    for (int mi = 0; mi < 8; ++mi) {                                          \
      bf8 afr = *(const bf8*)&As[CUR][(mi * 16 + l15) * 32 + (l4 ^ fA) * 8];  \
      acc[mi] = __builtin_amdgcn_mfma_f32_16x16x32_bf16(afr, bfr, acc[mi], 0, 0, 0); \
    }                                                                         \
    if ((S) + 1 < NS) G1_LSTOREA(CUR ^ 1);                                    \
    __syncthreads();                                                          \
  }

  const int fA = (l15 >> 2) & 3;        // A-read swizzle term
  const int NS = C_ / 32;               // 48 K-steps

  G1_GLOADA(0);
  G1_GLOADB(0, xs0);
  G1_LSTOREA(0);
  __syncthreads();

  for (int sp = 0; sp < NS / 2; ++sp) {
    G1_STEP(2 * sp,     xs0, xs1, 0);
    G1_STEP(2 * sp + 1, xs1, xs0, 1);
  }

  // epilogue: +hconst, relu, LN over 128 h (per t-col), tanh, bf16 store
  const int t = t0 + w * 16 + l15;
  float sum = 0.f, ssq = 0.f;
#pragma unroll
  for (int mi = 0; mi < 8; ++mi) {
    float4 h4 = *(const float4*)(hconst + b * H_ + mi * 16 + l4 * 4);
    const float* hp = (const float*)&h4;
#pragma unroll
    for (int reg = 0; reg < 4; ++reg) {
      float v = fmaxf(acc[mi][reg] + hp[reg], 0.f);
      acc[mi][reg] = v;
      sum += v;
      ssq += v * v;
    }
  }
  sum += __shfl_xor(sum, 16); sum += __shfl_xor(sum, 32);
  ssq += __shfl_xor(ssq, 16); ssq += __shfl_xor(ssq, 32);
  const float mean = sum * (1.f / 128.f);
  const float rstd = rsqrtf(ssq * (1.f / 128.f) - mean * mean + 1e-5f);
  if (t < T_) {
    unsigned short* dst = hlnT + ((size_t)b * T_ + t) * H_;
#pragma unroll
    for (int mi = 0; mi < 8; ++mi) {
      float4 g4 = *(const float4*)(g1 + mi * 16 + l4 * 4);
      float4 e4 = *(const float4*)(be1 + mi * 16 + l4 * 4);
      const float* gp = (const float*)&g4;
      const float* ep = (const float*)&e4;
      bf4 p;
#pragma unroll
      for (int reg = 0; reg < 4; ++reg) {
        float o = tanhf((acc[mi][reg] - mean) * rstd * gp[reg] + ep[reg]);
        p[reg] = (short)f2b(o);
      }
      *(bf4*)&dst[mi * 16 + l4 * 4] = p;
    }
  }
}

// ---------------- K4: MFMA GEMM2 (alpha=w2@hln) + FIXED-MAX softmax + pooling -
// grid (24 c-tiles of 64, B, NT=4 parts of 512t) = 1536 blocks (R13 optimum).
// A-operand (w2, pre-scaled by log2e) in REGISTERS; LDS = Hs 32KB only.
// Pooling x loads from bf16 xb (half bytes; +~4e-3 absmax, within threshold).
// e = exp2(acc - Mc), Mc = wl1*log2e.
__global__ __launch_bounds__(256) void k_gemm2_pool(
    const unsigned short* __restrict__ xb, const float* __restrict__ mask,
    const float* __restrict__ w2, const unsigned short* __restrict__ hlnT,
    const float* __restrict__ wl1,
    float* __restrict__ ps0, float* __restrict__ ps1, float* __restrict__ ps2) {
  __shared__ __align__(16) short Hs[2][64 * 128];   // [t][h] swizzled, 2x16KB
  const int b = blockIdx.y;
  const int c0 = blockIdx.x * 64;
  const int part = blockIdx.z;
  const int tb = part * 512;
  const int te = min(tb + 512, T_);
  const int tid = threadIdx.x;
  const int lane = tid & 63;
  const int w = tid >> 6;
  const int l15 = lane & 15;
  const int l4 = lane >> 4;

  // A-frags in registers: af[ks] = bf16(log2e * w2[c0+w*16+l15][(ks*4+l4)*8..])
  bf8 af[4];
#pragma unroll
  for (int ks = 0; ks < 4; ++ks) {
    const float* src = w2 + (size_t)(c0 + w * 16 + l15) * H_ + (ks * 4 + l4) * 8;
    float4 v0 = *(const float4*)src;
    float4 v1 = *(const float4*)(src + 4);
    bf8 p;
    p[0] = (short)f2b(v0.x * LOG2E_); p[1] = (short)f2b(v0.y * LOG2E_);
    p[2] = (short)f2b(v0.z * LOG2E_); p[3] = (short)f2b(v0.w * LOG2E_);
    p[4] = (short)f2b(v1.x * LOG2E_); p[5] = (short)f2b(v1.y * LOG2E_);
    p[6] = (short)f2b(v1.z * LOG2E_); p[7] = (short)f2b(v1.w * LOG2E_);
    af[ks] = p;
  }

  // static per-row log2-domain logit bound Mc (exp2 arg <= ~0)
  float Mc[4];
  {
    float4 m4 = *(const float4*)(wl1 + c0 + w * 16 + l4 * 4);
    Mc[0] = m4.x; Mc[1] = m4.y; Mc[2] = m4.z; Mc[3] = m4.w;
  }

  float s0[4], s1[4], s2[4];
#pragma unroll
  for (int r = 0; r < 4; ++r) { s0[r] = 0.f; s1[r] = 0.f; s2[r] = 0.f; }

  bf8 hreg[4];
#define G2_HLOAD(T0)                                                          \
  {                                                                           \
    _Pragma("unroll")                                                         \
    for (int q = 0; q < 4; ++q) {                                             \
      int idx = q * 256 + tid;                                                \
      int row = idx >> 4, slot = idx & 15;                                    \
      int t = (T0) + row;                                                     \
      if (t > T_ - 1) t = T_ - 1;                                             \
      hreg[q] = *(const bf8*)(hlnT + ((size_t)b * T_ + t) * H_ + slot * 8);   \
    }                                                                         \
  }
#define G2_HSTORE(BUF)                                                        \
  {                                                                           \
    _Pragma("unroll")                                                         \
    for (int q = 0; q < 4; ++q) {                                             \
      int idx = q * 256 + tid;                                                \
      int row = idx >> 4, slot = idx & 15;                                    \
      *(bf8*)&Hs[BUF][row * 128 + (slot ^ (row & 15)) * 8] = hreg[q];         \
    }                                                                         \
  }

  G2_HLOAD(tb);
  G2_HSTORE(0);
  __syncthreads();

  const int NCH = (te - tb + 63) / 64;   // <= 8
  for (int ch = 0; ch < NCH; ++ch) {
    const int t0 = tb + ch * 64;
    const int cur = ch & 1;
    if (ch + 1 < NCH) G2_HLOAD(t0 + 64);

    // issue-early: mask + xb loads for this chunk, consumed after MFMA
    float mk[4];
    int tcol[4];
#pragma unroll
    for (int nj = 0; nj < 4; ++nj) {
      int t = t0 + nj * 16 + l15;
      tcol[nj] = (t < T_) ? t : (T_ - 1);
      mk[nj] = (t < T_) ? mask[(size_t)b * T_ + t] : 0.f;
    }
    float xv[4][4];
#pragma unroll
    for (int reg = 0; reg < 4; ++reg) {
      const int c = c0 + w * 16 + l4 * 4 + reg;
      const unsigned short* xrow = xb + ((size_t)(b * C_ + c)) * T_;
#pragma unroll
      for (int nj = 0; nj < 4; ++nj) xv[reg][nj] = b2f(xrow[tcol[nj]]);
    }

    f4 acc[4];
#pragma unroll
    for (int nj = 0; nj < 4; ++nj) { f4 z = {0.f, 0.f, 0.f, 0.f}; acc[nj] = z; }

#pragma unroll
    for (int ks = 0; ks < 4; ++ks) {
      const int sw = (ks * 4 + l4) ^ l15;   // row&15 == l15 for B rows
      bf8 bb[4];
#pragma unroll
      for (int nj = 0; nj < 4; ++nj)
        bb[nj] = *(const bf8*)&Hs[cur][(nj * 16 + l15) * 128 + sw * 8];
#pragma unroll
      for (int nj = 0; nj < 4; ++nj)
        acc[nj] = __builtin_amdgcn_mfma_f32_16x16x32_bf16(af[ks], bb[nj], acc[nj], 0, 0, 0);
    }

    // epilogue: fixed-max exp2 + pooled partial sums (no serial chain)
#pragma unroll
    for (int reg = 0; reg < 4; ++reg) {
      float a0 = s0[reg], a1 = s1[reg], a2 = s2[reg];
#pragma unroll
      for (int nj = 0; nj < 4; ++nj) {
        float e = (mk[nj] != 0.f) ? exp2f(acc[nj][reg] - Mc[reg]) : 0.f;
        float xvv = xv[reg][nj];
        a0 += e; a1 += e * xvv; a2 += e * xvv * xvv;
      }
      s0[reg] = a0; s1[reg] = a1; s2[reg] = a2;
    }

    // HSTORE after the epilogue: the epilogue VALU hides this iter's HLOAD
    // latency; buffer cur^1 was drained at the previous iteration's barrier.
    if (ch + 1 < NCH) G2_HSTORE(cur ^ 1);
    __syncthreads();
  }

  // merge the 16 lanes (t-cols) of each row group: plain adds
#pragma unroll
  for (int off = 1; off < 16; off <<= 1) {
#pragma unroll
    for (int r = 0; r < 4; ++r) {
      s0[r] += __shfl_xor(s0[r], off);
      s1[r] += __shfl_xor(s1[r], off);
      s2[r] += __shfl_xor(s2[r], off);
    }
  }
  if (l15 == 0) {
#pragma unroll
    for (int reg = 0; reg < 4; ++reg) {
      const int c = c0 + w * 16 + l4 * 4 + reg;
      const size_t j = ((size_t)(b * NT_ + part)) * C_ + c;
      ps0[j] = s0[reg]; ps1[j] = s1[reg]; ps2[j] = s2[reg];
    }
  }
}

// ---------------- K5: merge NT partials -> pooled stats -> final LN -> out ----
// one block per b; thread handles 6 c (c = i*256+tid); LN over 2C jointly.
__global__ __launch_bounds__(256) void k_pool_ln(
    const float* __restrict__ ps0, const float* __restrict__ ps1,
    const float* __restrict__ ps2, const float* __restrict__ g2,
    const float* __restrict__ be2, float* __restrict__ out) {
  __shared__ float rs[8];
  const int b = blockIdx.x;
  const int tid = threadIdx.x;
  const int lane = tid & 63;
  const int wave = tid >> 6;
  float mv[6], sv[6];
  float s = 0.f, q = 0.f;
#pragma unroll
  for (int i = 0; i < 6; ++i) {
    const int c = i * 256 + tid;
    float a0 = 0.f, a1 = 0.f, a2 = 0.f;
#pragma unroll
    for (int p = 0; p < NT_; ++p) {
      const size_t j = ((size_t)(b * NT_ + p)) * C_ + c;
      a0 += ps0[j]; a1 += ps1[j]; a2 += ps2[j];
    }
    float mean = a1 / a0;
    float var = a2 / a0 - mean * mean;
    float sd = sqrtf(fmaxf(var, 1e-5f));
    mv[i] = mean; sv[i] = sd;
    s += mean + sd;
    q += mean * mean + sd * sd;
  }
#pragma unroll
  for (int off = 32; off; off >>= 1) {
    s += __shfl_xor(s, off);
    q += __shfl_xor(q, off);
  }
  if (lane == 0) { rs[wave] = s; rs[4 + wave] = q; }
  __syncthreads();
  s = rs[0] + rs[1] + rs[2] + rs[3];
  q = rs[4] + rs[5] + rs[6] + rs[7];
  const float mu = s * (1.f / C2_);
  const float var = q * (1.f / C2_) - mu * mu;
  const float rstd = rsqrtf(var + 1e-5f);
#pragma unroll
  for (int i = 0; i < 6; ++i) {
    const int c = i * 256 + tid;
    out[b * C2_ + c]      = (mv[i] - mu) * rstd * g2[c] + be2[c];
    out[b * C2_ + C_ + c] = (sv[i] - mu) * rstd * g2[C_ + c] + be2[C_ + c];
  }
}

extern "C" void kernel_launch(void* const* d_in, const int* in_sizes, int n_in,
                              void* d_out, int out_size, void* d_ws, size_t ws_size,
                              hipStream_t stream) {
  const float* x    = (const float*)d_in[0];
  const float* mask = (const float*)d_in[1];
  const float* w1   = (const float*)d_in[2];
  const float* b1   = (const float*)d_in[3];
  const float* g1   = (const float*)d_in[4];
  const float* be1  = (const float*)d_in[5];
  const float* w2   = (const float*)d_in[6];
  // d_in[7] = b2: per-(b,c) constant on softmax logits -> softmax-invariant, dropped
  const float* g2   = (const float*)d_in[8];
  const float* be2  = (const float*)d_in[9];
  float* out = (float*)d_out;

  float* ws     = (float*)d_ws;
  float* mean0  = ws;                   // B*C
  float* std0   = mean0 + B_ * C_;      // B*C
  float* hconst = std0 + B_ * C_;       // B*H
  float* wl1    = hconst + B_ * H_;     // C
  float* ps0    = wl1 + C_;             // B*NT*C each:
  float* ps1    = ps0 + B_ * NT_ * C_;
  float* ps2    = ps1 + B_ * NT_ * C_;
  unsigned short* hlnT = (unsigned short*)(ps2 + B_ * NT_ * C_);        // B*T*H bf16
  unsigned short* xb   = hlnT + (size_t)B_ * T_ * H_;                   // B*C*T bf16, 98MB

  k_stats_cvt<<<dim3(B_ * C_ / 4), dim3(256), 0, stream>>>(x, mask, mean0, std0, xb);
  k_hconst_wl1<<<dim3(B_ * H_ / 4 + C_ / 4), dim3(256), 0, stream>>>(
      w1, b1, mean0, std0, w2, hconst, wl1);
  k_gemm1_ln<<<dim3((T_ + 63) / 64, B_), dim3(256), 0, stream>>>(xb, w1, hconst, g1, be1, hlnT);
  k_gemm2_pool<<<dim3(C_ / 64, B_, NT_), dim3(256), 0, stream>>>(xb, mask, w2, hlnT, wl1,
                                                                 ps0, ps1, ps2);
  k_pool_ln<<<dim3(B_), dim3(256), 0, stream>>>(ps0, ps1, ps2, g2, be2, out);
}

// Round 18
// 141.564 us; speedup vs baseline: 1.2332x; 1.2332x over previous
//
#include <hip/hip_runtime.h>
#include <hip/hip_bf16.h>
#include <math.h>

constexpr int B_  = 16;
constexpr int C_  = 1536;
constexpr int T_  = 2000;
constexpr int H_  = 128;
constexpr int C3_ = 3 * C_;   // 4608
constexpr int C2_ = 2 * C_;   // 3072
constexpr int NT_ = 4;        // t-parts for gemm2 (512 t each)
constexpr float LOG2E_ = 1.44269504088896340736f;

typedef short bf8 __attribute__((ext_vector_type(8)));   // 8 bf16 (4 VGPR) MFMA A/B frag
typedef short bf4 __attribute__((ext_vector_type(4)));   // 4 bf16 (8B)
typedef float f4  __attribute__((ext_vector_type(4)));   // MFMA C/D frag

// fp32 -> bf16 RTNE (hardware cvt; compiler pairs into v_cvt_pk_bf16_f32)
__device__ inline unsigned short f2b(float f) {
  __bf16 h = (__bf16)f;
  return __builtin_bit_cast(unsigned short, h);
}

// ---------------- K1: masked per-(b,c) mean/std over T (one wave per row) ----
__global__ __launch_bounds__(256) void k_stats(
    const float* __restrict__ x, const float* __restrict__ mask,
    float* __restrict__ mean0, float* __restrict__ std0) {
  const int wave = threadIdx.x >> 6;
  const int lane = threadIdx.x & 63;
  const int row = blockIdx.x * 4 + wave;      // b*C + c
  const int b = row / C_;
  const float4* xr = (const float4*)(x + (size_t)row * T_);
  const float4* mr = (const float4*)(mask + (size_t)b * T_);
  float sm = 0.f, s1 = 0.f, s2 = 0.f;
  for (int i = lane; i < T_ / 4; i += 64) {
    float4 xv = xr[i];
    float4 mv = mr[i];
    sm += mv.x + mv.y + mv.z + mv.w;
    s1 += mv.x * xv.x + mv.y * xv.y + mv.z * xv.z + mv.w * xv.w;
    s2 += mv.x * xv.x * xv.x + mv.y * xv.y * xv.y + mv.z * xv.z * xv.z + mv.w * xv.w * xv.w;
  }
#pragma unroll
  for (int off = 32; off; off >>= 1) {
    sm += __shfl_xor(sm, off);
    s1 += __shfl_xor(s1, off);
    s2 += __shfl_xor(s2, off);
  }
  if (lane == 0) {
    float mean = s1 / sm;
    float var = s2 / sm - mean * mean;
    mean0[row] = mean;
    std0[row] = sqrtf(fmaxf(var, 1e-5f));
  }
}

// ---------------- K2: hconst GEMV + wl1 L1-norms in ONE launch ----------------
// wl1 is pre-scaled by log2(e) to match gemm2's log2-domain logits.
__global__ __launch_bounds__(256) void k_hconst_wl1(
    const float* __restrict__ w1, const float* __restrict__ b1,
    const float* __restrict__ mean0, const float* __restrict__ std0,
    const float* __restrict__ w2,
    float* __restrict__ hconst, float* __restrict__ wl1) {
  const int wave = threadIdx.x >> 6;
  const int lane = threadIdx.x & 63;
  if (blockIdx.x < B_ * H_ / 4) {
    const int idx = blockIdx.x * 4 + wave;      // b*H + h
    const int b = idx >> 7;
    const int h = idx & (H_ - 1);
    const float* wm  = w1 + (size_t)h * C3_ + C_;
    const float* wsd = wm + C_;
    const float* mn = mean0 + b * C_;
    const float* sd = std0 + b * C_;
    float s = 0.f;
    for (int c = lane; c < C_; c += 64)
      s += wm[c] * mn[c] + wsd[c] * sd[c];
#pragma unroll
    for (int off = 32; off; off >>= 1) s += __shfl_xor(s, off);
    if (lane == 0) hconst[idx] = s + b1[h];
  } else {
    const int c = (blockIdx.x - B_ * H_ / 4) * 4 + wave;
    const float* wr = w2 + (size_t)c * H_;
    float s = fabsf(wr[lane]) + fabsf(wr[lane + 64]);
#pragma unroll
    for (int off = 32; off; off >>= 1) s += __shfl_xor(s, off);
    if (lane == 0) wl1[c] = s * LOG2E_;
  }
}

// ---------------- K3: MFMA GEMM1 (reg-B) + relu + LN(H) + tanh -> hlnT bf16 ---
// block 256 thr (4 waves), tile 128h x 64t; wave w owns t-slice w*16..+15.
// B-operand direct to registers (R13 win); A (w1) in LDS, conflict-free.
// (R17's bf16-x variant regressed: halved coalescing segments, extra write
// stream; reverted to fp32 x + in-kernel RTNE.)
__global__ __launch_bounds__(256) void k_gemm1_ln(
    const float* __restrict__ x, const float* __restrict__ w1,
    const float* __restrict__ hconst, const float* __restrict__ g1,
    const float* __restrict__ be1, unsigned short* __restrict__ hlnT) {
  __shared__ __align__(16) short As[2][128 * 32];
  const int b = blockIdx.y;
  const int t0 = blockIdx.x * 64;
  const int tid = threadIdx.x;
  const int lane = tid & 63;
  const int w = tid >> 6;
  const int l15 = lane & 15;
  const int l4 = lane >> 4;
  // this lane's t-column (clamped; t>=T_ columns produce garbage that is
  // never stored -- LN is per t-column so no contamination)
  const int tcl = min(t0 + w * 16 + l15, T_ - 1);
  const float* xcol = x + (size_t)b * C_ * T_ + tcl;

  float4 va[4];
  float xs0[8], xs1[8];

  f4 acc[8];
#pragma unroll
  for (int mi = 0; mi < 8; ++mi) { f4 z = {0.f, 0.f, 0.f, 0.f}; acc[mi] = z; }

#define G1_GLOADA(K0)                                                         \
  {                                                                           \
    _Pragma("unroll")                                                         \
    for (int q = 0; q < 4; ++q) {                                             \
      int idx = q * 256 + tid;                                                \
      int row = idx >> 3, j4 = idx & 7;                                       \
      va[q] = *(const float4*)(w1 + (size_t)row * C3_ + (K0) + j4 * 4);       \
    }                                                                         \
  }
#define G1_GLOADB(K0, XS)                                                     \
  {                                                                           \
    const float* xq = xcol + ((size_t)(K0) + l4 * 8) * T_;                    \
    _Pragma("unroll")                                                         \
    for (int j = 0; j < 8; ++j) XS[j] = xq[(size_t)j * T_];                   \
  }
#define G1_LSTOREA(BUF)                                                       \
  {                                                                           \
    _Pragma("unroll")                                                         \
    for (int q = 0; q < 4; ++q) {                                             \
      int idx = q * 256 + tid;                                                \
      int row = idx >> 3, j4 = idx & 7;                                       \
      int slot = (j4 >> 1) ^ ((row >> 2) & 3);                                \
      bf4 p;                                                                  \
      p[0] = (short)f2b(va[q].x); p[1] = (short)f2b(va[q].y);                 \
      p[2] = (short)f2b(va[q].z); p[3] = (short)f2b(va[q].w);                 \
      *(bf4*)&As[BUF][row * 32 + slot * 8 + (j4 & 1) * 4] = p;                \
    }                                                                         \
  }
// one K-step: prefetch A+B for step s+1, compute step s from regs+LDS[CUR]
#define G1_STEP(S, XSCUR, XSNXT, CUR)                                         \
  {                                                                           \
    if ((S) + 1 < NS) {                                                       \
      G1_GLOADA(((S) + 1) * 32);                                              \
      G1_GLOADB(((S) + 1) * 32, XSNXT);                                       \
    }                                                                         \
    bf8 bfr;                                                                  \
    _Pragma("unroll")                                                         \
    for (int j = 0; j < 8; ++j) bfr[j] = (short)f2b(XSCUR[j]);                \
    _Pragma("unroll")                                                         \
    for (int mi = 0; mi < 8; ++mi) {                                          \
      bf8 afr = *(const bf8*)&As[CUR][(mi * 16 + l15) * 32 + (l4 ^ fA) * 8];  \
      acc[mi] = __builtin_amdgcn_mfma_f32_16x16x32_bf16(afr, bfr, acc[mi], 0, 0, 0); \
    }                                                                         \
    if ((S) + 1 < NS) G1_LSTOREA(CUR ^ 1);                                    \
    __syncthreads();                                                          \
  }

  const int fA = (l15 >> 2) & 3;        // A-read swizzle term
  const int NS = C_ / 32;               // 48 K-steps

  G1_GLOADA(0);
  G1_GLOADB(0, xs0);
  G1_LSTOREA(0);
  __syncthreads();

  for (int sp = 0; sp < NS / 2; ++sp) {
    G1_STEP(2 * sp,     xs0, xs1, 0);
    G1_STEP(2 * sp + 1, xs1, xs0, 1);
  }

  // epilogue: +hconst, relu, LN over 128 h (per t-col), tanh, bf16 store
  const int t = t0 + w * 16 + l15;
  float sum = 0.f, ssq = 0.f;
#pragma unroll
  for (int mi = 0; mi < 8; ++mi) {
    float4 h4 = *(const float4*)(hconst + b * H_ + mi * 16 + l4 * 4);
    const float* hp = (const float*)&h4;
#pragma unroll
    for (int reg = 0; reg < 4; ++reg) {
      float v = fmaxf(acc[mi][reg] + hp[reg], 0.f);
      acc[mi][reg] = v;
      sum += v;
      ssq += v * v;
    }
  }
  sum += __shfl_xor(sum, 16); sum += __shfl_xor(sum, 32);
  ssq += __shfl_xor(ssq, 16); ssq += __shfl_xor(ssq, 32);
  const float mean = sum * (1.f / 128.f);
  const float rstd = rsqrtf(ssq * (1.f / 128.f) - mean * mean + 1e-5f);
  if (t < T_) {
    unsigned short* dst = hlnT + ((size_t)b * T_ + t) * H_;
#pragma unroll
    for (int mi = 0; mi < 8; ++mi) {
      float4 g4 = *(const float4*)(g1 + mi * 16 + l4 * 4);
      float4 e4 = *(const float4*)(be1 + mi * 16 + l4 * 4);
      const float* gp = (const float*)&g4;
      const float* ep = (const float*)&e4;
      bf4 p;
#pragma unroll
      for (int reg = 0; reg < 4; ++reg) {
        float o = tanhf((acc[mi][reg] - mean) * rstd * gp[reg] + ep[reg]);
        p[reg] = (short)f2b(o);
      }
      *(bf4*)&dst[mi * 16 + l4 * 4] = p;
    }
  }
}

// ---------------- K4: MFMA GEMM2 (alpha=w2@hln) + FIXED-MAX softmax + pooling -
// R16 structure + T1 bijective XCD swizzle: flat grid 1536 = 8 XCDs x 192.
// Each XCD owns 8 complete (b,part) groups x 24 c-tiles, so the 24 blocks
// sharing one 256KB hlnT slice + mask row all hit the SAME per-XCD L2
// (default round-robin fetched it up to 8x from HBM).
// A-operand (w2, pre-scaled by log2e) in REGISTERS; LDS = Hs 32KB only.
// e = exp2(acc - Mc), Mc = wl1*log2e.
__global__ __launch_bounds__(256) void k_gemm2_pool(
    const float* __restrict__ x, const float* __restrict__ mask,
    const float* __restrict__ w2, const unsigned short* __restrict__ hlnT,
    const float* __restrict__ wl1,
    float* __restrict__ ps0, float* __restrict__ ps1, float* __restrict__ ps2) {
  __shared__ __align__(16) short Hs[2][64 * 128];   // [t][h] swizzled, 2x16KB
  // bijective XCD swizzle (1536 % 8 == 0)
  const int g = blockIdx.x;
  const int wid = (g & 7) * 192 + (g >> 3);   // 0..1535
  const int c0 = (wid % 24) * 64;
  const int rest = wid / 24;                  // 0..63
  const int b = rest & 15;
  const int part = rest >> 4;                 // 0..3
  const int tb = part * 512;
  const int te = min(tb + 512, T_);
  const int tid = threadIdx.x;
  const int lane = tid & 63;
  const int w = tid >> 6;
  const int l15 = lane & 15;
  const int l4 = lane >> 4;

  // A-frags in registers: af[ks] = bf16(log2e * w2[c0+w*16+l15][(ks*4+l4)*8..])
  bf8 af[4];
#pragma unroll
  for (int ks = 0; ks < 4; ++ks) {
    const float* src = w2 + (size_t)(c0 + w * 16 + l15) * H_ + (ks * 4 + l4) * 8;
    float4 v0 = *(const float4*)src;
    float4 v1 = *(const float4*)(src + 4);
    bf8 p;
    p[0] = (short)f2b(v0.x * LOG2E_); p[1] = (short)f2b(v0.y * LOG2E_);
    p[2] = (short)f2b(v0.z * LOG2E_); p[3] = (short)f2b(v0.w * LOG2E_);
    p[4] = (short)f2b(v1.x * LOG2E_); p[5] = (short)f2b(v1.y * LOG2E_);
    p[6] = (short)f2b(v1.z * LOG2E_); p[7] = (short)f2b(v1.w * LOG2E_);
    af[ks] = p;
  }

  // static per-row log2-domain logit bound Mc (exp2 arg <= ~0)
  float Mc[4];
  {
    float4 m4 = *(const float4*)(wl1 + c0 + w * 16 + l4 * 4);
    Mc[0] = m4.x; Mc[1] = m4.y; Mc[2] = m4.z; Mc[3] = m4.w;
  }

  float s0[4], s1[4], s2[4];
#pragma unroll
  for (int r = 0; r < 4; ++r) { s0[r] = 0.f; s1[r] = 0.f; s2[r] = 0.f; }

  bf8 hreg[4];
#define G2_HLOAD(T0)                                                          \
  {                                                                           \
    _Pragma("unroll")                                                         \
    for (int q = 0; q < 4; ++q) {                                             \
      int idx = q * 256 + tid;                                                \
      int row = idx >> 4, slot = idx & 15;                                    \
      int t = (T0) + row;                                                     \
      if (t > T_ - 1) t = T_ - 1;                                             \
      hreg[q] = *(const bf8*)(hlnT + ((size_t)b * T_ + t) * H_ + slot * 8);   \
    }                                                                         \
  }
#define G2_HSTORE(BUF)                                                        \
  {                                                                           \
    _Pragma("unroll")                                                         \
    for (int q = 0; q < 4; ++q) {                                             \
      int idx = q * 256 + tid;                                                \
      int row = idx >> 4, slot = idx & 15;                                    \
      *(bf8*)&Hs[BUF][row * 128 + (slot ^ (row & 15)) * 8] = hreg[q];         \
    }                                                                         \
  }

  G2_HLOAD(tb);
  G2_HSTORE(0);
  __syncthreads();

  const int NCH = (te - tb + 63) / 64;   // <= 8
  for (int ch = 0; ch < NCH; ++ch) {
    const int t0 = tb + ch * 64;
    const int cur = ch & 1;
    if (ch + 1 < NCH) G2_HLOAD(t0 + 64);

    // issue-early: mask + x loads for this chunk, consumed after MFMA
    float mk[4];
    int tcol[4];
#pragma unroll
    for (int nj = 0; nj < 4; ++nj) {
      int t = t0 + nj * 16 + l15;
      tcol[nj] = (t < T_) ? t : (T_ - 1);
      mk[nj] = (t < T_) ? mask[(size_t)b * T_ + t] : 0.f;
    }
    float xv[4][4];
#pragma unroll
    for (int reg = 0; reg < 4; ++reg) {
      const int c = c0 + w * 16 + l4 * 4 + reg;
      const float* xrow = x + ((size_t)(b * C_ + c)) * T_;
#pragma unroll
      for (int nj = 0; nj < 4; ++nj) xv[reg][nj] = xrow[tcol[nj]];
    }

    f4 acc[4];
#pragma unroll
    for (int nj = 0; nj < 4; ++nj) { f4 z = {0.f, 0.f, 0.f, 0.f}; acc[nj] = z; }

#pragma unroll
    for (int ks = 0; ks < 4; ++ks) {
      const int sw = (ks * 4 + l4) ^ l15;   // row&15 == l15 for B rows
      bf8 bb[4];
#pragma unroll
      for (int nj = 0; nj < 4; ++nj)
        bb[nj] = *(const bf8*)&Hs[cur][(nj * 16 + l15) * 128 + sw * 8];
#pragma unroll
      for (int nj = 0; nj < 4; ++nj)
        acc[nj] = __builtin_amdgcn_mfma_f32_16x16x32_bf16(af[ks], bb[nj], acc[nj], 0, 0, 0);
    }

    // epilogue: fixed-max exp2 + pooled partial sums (no serial chain)
#pragma unroll
    for (int reg = 0; reg < 4; ++reg) {
      float a0 = s0[reg], a1 = s1[reg], a2 = s2[reg];
#pragma unroll
      for (int nj = 0; nj < 4; ++nj) {
        float e = (mk[nj] != 0.f) ? exp2f(acc[nj][reg] - Mc[reg]) : 0.f;
        float xvv = xv[reg][nj];
        a0 += e; a1 += e * xvv; a2 += e * xvv * xvv;
      }
      s0[reg] = a0; s1[reg] = a1; s2[reg] = a2;
    }

    // HSTORE after the epilogue: the epilogue VALU hides this iter's HLOAD
    // latency; buffer cur^1 was drained at the previous iteration's barrier.
    if (ch + 1 < NCH) G2_HSTORE(cur ^ 1);
    __syncthreads();
  }

  // merge the 16 lanes (t-cols) of each row group: plain adds
#pragma unroll
  for (int off = 1; off < 16; off <<= 1) {
#pragma unroll
    for (int r = 0; r < 4; ++r) {
      s0[r] += __shfl_xor(s0[r], off);
      s1[r] += __shfl_xor(s1[r], off);
      s2[r] += __shfl_xor(s2[r], off);
    }
  }
  if (l15 == 0) {
#pragma unroll
    for (int reg = 0; reg < 4; ++reg) {
      const int c = c0 + w * 16 + l4 * 4 + reg;
      const size_t j = ((size_t)(b * NT_ + part)) * C_ + c;
      ps0[j] = s0[reg]; ps1[j] = s1[reg]; ps2[j] = s2[reg];
    }
  }
}

// ---------------- K5: merge NT partials -> pooled stats -> final LN -> out ----
// one block per b; thread handles 6 c (c = i*256+tid); LN over 2C jointly.
__global__ __launch_bounds__(256) void k_pool_ln(
    const float* __restrict__ ps0, const float* __restrict__ ps1,
    const float* __restrict__ ps2, const float* __restrict__ g2,
    const float* __restrict__ be2, float* __restrict__ out) {
  __shared__ float rs[8];
  const int b = blockIdx.x;
  const int tid = threadIdx.x;
  const int lane = tid & 63;
  const int wave = tid >> 6;
  float mv[6], sv[6];
  float s = 0.f, q = 0.f;
#pragma unroll
  for (int i = 0; i < 6; ++i) {
    const int c = i * 256 + tid;
    float a0 = 0.f, a1 = 0.f, a2 = 0.f;
#pragma unroll
    for (int p = 0; p < NT_; ++p) {
      const size_t j = ((size_t)(b * NT_ + p)) * C_ + c;
      a0 += ps0[j]; a1 += ps1[j]; a2 += ps2[j];
    }
    float mean = a1 / a0;
    float var = a2 / a0 - mean * mean;
    float sd = sqrtf(fmaxf(var, 1e-5f));
    mv[i] = mean; sv[i] = sd;
    s += mean + sd;
    q += mean * mean + sd * sd;
  }
#pragma unroll
  for (int off = 32; off; off >>= 1) {
    s += __shfl_xor(s, off);
    q += __shfl_xor(q, off);
  }
  if (lane == 0) { rs[wave] = s; rs[4 + wave] = q; }
  __syncthreads();
  s = rs[0] + rs[1] + rs[2] + rs[3];
  q = rs[4] + rs[5] + rs[6] + rs[7];
  const float mu = s * (1.f / C2_);
  const float var = q * (1.f / C2_) - mu * mu;
  const float rstd = rsqrtf(var + 1e-5f);
#pragma unroll
  for (int i = 0; i < 6; ++i) {
    const int c = i * 256 + tid;
    out[b * C2_ + c]      = (mv[i] - mu) * rstd * g2[c] + be2[c];
    out[b * C2_ + C_ + c] = (sv[i] - mu) * rstd * g2[C_ + c] + be2[C_ + c];
  }
}

extern "C" void kernel_launch(void* const* d_in, const int* in_sizes, int n_in,
                              void* d_out, int out_size, void* d_ws, size_t ws_size,
                              hipStream_t stream) {
  const float* x    = (const float*)d_in[0];
  const float* mask = (const float*)d_in[1];
  const float* w1   = (const float*)d_in[2];
  const float* b1   = (const float*)d_in[3];
  const float* g1   = (const float*)d_in[4];
  const float* be1  = (const float*)d_in[5];
  const float* w2   = (const float*)d_in[6];
  // d_in[7] = b2: per-(b,c) constant on softmax logits -> softmax-invariant, dropped
  const float* g2   = (const float*)d_in[8];
  const float* be2  = (const float*)d_in[9];
  float* out = (float*)d_out;

  float* ws     = (float*)d_ws;
  float* mean0  = ws;                   // B*C
  float* std0   = mean0 + B_ * C_;      // B*C
  float* hconst = std0 + B_ * C_;       // B*H
  float* wl1    = hconst + B_ * H_;     // C
  float* ps0    = wl1 + C_;             // B*NT*C each:
  float* ps1    = ps0 + B_ * NT_ * C_;
  float* ps2    = ps1 + B_ * NT_ * C_;
  unsigned short* hlnT = (unsigned short*)(ps2 + B_ * NT_ * C_);  // B*T*H bf16

  k_stats<<<dim3(B_ * C_ / 4), dim3(256), 0, stream>>>(x, mask, mean0, std0);
  k_hconst_wl1<<<dim3(B_ * H_ / 4 + C_ / 4), dim3(256), 0, stream>>>(
      w1, b1, mean0, std0, w2, hconst, wl1);
  k_gemm1_ln<<<dim3((T_ + 63) / 64, B_), dim3(256), 0, stream>>>(x, w1, hconst, g1, be1, hlnT);
  k_gemm2_pool<<<dim3(24 * B_ * NT_), dim3(256), 0, stream>>>(x, mask, w2, hlnT, wl1,
                                                              ps0, ps1, ps2);
  k_pool_ln<<<dim3(B_), dim3(256), 0, stream>>>(ps0, ps1, ps2, g2, be2, out);
}

// Round 19
// 134.927 us; speedup vs baseline: 1.2939x; 1.0492x over previous
//
#include <hip/hip_runtime.h>
#include <hip/hip_bf16.h>
#include <math.h>

constexpr int B_  = 16;
constexpr int C_  = 1536;
constexpr int T_  = 2000;
constexpr int H_  = 128;
constexpr int C3_ = 3 * C_;   // 4608
constexpr int C2_ = 2 * C_;   // 3072
constexpr int NT_ = 4;        // t-parts for gemm2 (512 t each)
constexpr float LOG2E_ = 1.44269504088896340736f;

typedef short bf8 __attribute__((ext_vector_type(8)));   // 8 bf16 (4 VGPR) MFMA A/B frag
typedef short bf4 __attribute__((ext_vector_type(4)));   // 4 bf16 (8B)
typedef float f4  __attribute__((ext_vector_type(4)));   // MFMA C/D frag

// fp32 -> bf16 RTNE (hardware cvt; compiler pairs into v_cvt_pk_bf16_f32)
__device__ inline unsigned short f2b(float f) {
  __bf16 h = (__bf16)f;
  return __builtin_bit_cast(unsigned short, h);
}

// ---------------- K1: masked per-(b,c) mean/std over T (one wave per row) ----
__global__ __launch_bounds__(256) void k_stats(
    const float* __restrict__ x, const float* __restrict__ mask,
    float* __restrict__ mean0, float* __restrict__ std0) {
  const int wave = threadIdx.x >> 6;
  const int lane = threadIdx.x & 63;
  const int row = blockIdx.x * 4 + wave;      // b*C + c
  const int b = row / C_;
  const float4* xr = (const float4*)(x + (size_t)row * T_);
  const float4* mr = (const float4*)(mask + (size_t)b * T_);
  float sm = 0.f, s1 = 0.f, s2 = 0.f;
  for (int i = lane; i < T_ / 4; i += 64) {
    float4 xv = xr[i];
    float4 mv = mr[i];
    sm += mv.x + mv.y + mv.z + mv.w;
    s1 += mv.x * xv.x + mv.y * xv.y + mv.z * xv.z + mv.w * xv.w;
    s2 += mv.x * xv.x * xv.x + mv.y * xv.y * xv.y + mv.z * xv.z * xv.z + mv.w * xv.w * xv.w;
  }
#pragma unroll
  for (int off = 32; off; off >>= 1) {
    sm += __shfl_xor(sm, off);
    s1 += __shfl_xor(s1, off);
    s2 += __shfl_xor(s2, off);
  }
  if (lane == 0) {
    float mean = s1 / sm;
    float var = s2 / sm - mean * mean;
    mean0[row] = mean;
    std0[row] = sqrtf(fmaxf(var, 1e-5f));
  }
}

// ---------------- K2: hconst GEMV + wl1 L1-norms in ONE launch ----------------
// wl1 is pre-scaled by log2(e) to match gemm2's log2-domain logits.
__global__ __launch_bounds__(256) void k_hconst_wl1(
    const float* __restrict__ w1, const float* __restrict__ b1,
    const float* __restrict__ mean0, const float* __restrict__ std0,
    const float* __restrict__ w2,
    float* __restrict__ hconst, float* __restrict__ wl1) {
  const int wave = threadIdx.x >> 6;
  const int lane = threadIdx.x & 63;
  if (blockIdx.x < B_ * H_ / 4) {
    const int idx = blockIdx.x * 4 + wave;      // b*H + h
    const int b = idx >> 7;
    const int h = idx & (H_ - 1);
    const float* wm  = w1 + (size_t)h * C3_ + C_;
    const float* wsd = wm + C_;
    const float* mn = mean0 + b * C_;
    const float* sd = std0 + b * C_;
    float s = 0.f;
    for (int c = lane; c < C_; c += 64)
      s += wm[c] * mn[c] + wsd[c] * sd[c];
#pragma unroll
    for (int off = 32; off; off >>= 1) s += __shfl_xor(s, off);
    if (lane == 0) hconst[idx] = s + b1[h];
  } else {
    const int c = (blockIdx.x - B_ * H_ / 4) * 4 + wave;
    const float* wr = w2 + (size_t)c * H_;
    float s = fabsf(wr[lane]) + fabsf(wr[lane + 64]);
#pragma unroll
    for (int off = 32; off; off >>= 1) s += __shfl_xor(s, off);
    if (lane == 0) wl1[c] = s * LOG2E_;
  }
}

// ---------------- K3: MFMA GEMM1 (reg-B, depth-2 prefetch) -> hlnT bf16 -------
// block 256 thr (4 waves), tile 128h x 64t; wave w owns t-slice w*16..+15.
// B-operand direct to registers. DEPTH-2 B PREFETCH via pack-then-refill:
// pack bfr from the buffer (freeing it), then refill the SAME buffer with
// step s+2's B -- doubles HBM-latency cover at zero register cost.
__global__ __launch_bounds__(256) void k_gemm1_ln(
    const float* __restrict__ x, const float* __restrict__ w1,
    const float* __restrict__ hconst, const float* __restrict__ g1,
    const float* __restrict__ be1, unsigned short* __restrict__ hlnT) {
  __shared__ __align__(16) short As[2][128 * 32];
  const int b = blockIdx.y;
  const int t0 = blockIdx.x * 64;
  const int tid = threadIdx.x;
  const int lane = tid & 63;
  const int w = tid >> 6;
  const int l15 = lane & 15;
  const int l4 = lane >> 4;
  // this lane's t-column (clamped; t>=T_ columns produce garbage that is
  // never stored -- LN is per t-column so no contamination)
  const int tcl = min(t0 + w * 16 + l15, T_ - 1);
  const float* xcol = x + (size_t)b * C_ * T_ + tcl;

  float4 va[4];
  float xs0[8], xs1[8];

  f4 acc[8];
#pragma unroll
  for (int mi = 0; mi < 8; ++mi) { f4 z = {0.f, 0.f, 0.f, 0.f}; acc[mi] = z; }

#define G1_GLOADA(K0)                                                         \
  {                                                                           \
    _Pragma("unroll")                                                         \
    for (int q = 0; q < 4; ++q) {                                             \
      int idx = q * 256 + tid;                                                \
      int row = idx >> 3, j4 = idx & 7;                                       \
      va[q] = *(const float4*)(w1 + (size_t)row * C3_ + (K0) + j4 * 4);       \
    }                                                                         \
  }
#define G1_GLOADB(K0, XS)                                                     \
  {                                                                           \
    const float* xq = xcol + ((size_t)(K0) + l4 * 8) * T_;                    \
    _Pragma("unroll")                                                         \
    for (int j = 0; j < 8; ++j) XS[j] = xq[(size_t)j * T_];                   \
  }
#define G1_LSTOREA(BUF)                                                       \
  {                                                                           \
    _Pragma("unroll")                                                         \
    for (int q = 0; q < 4; ++q) {                                             \
      int idx = q * 256 + tid;                                                \
      int row = idx >> 3, j4 = idx & 7;                                       \
      int slot = (j4 >> 1) ^ ((row >> 2) & 3);                                \
      bf4 p;                                                                  \
      p[0] = (short)f2b(va[q].x); p[1] = (short)f2b(va[q].y);                 \
      p[2] = (short)f2b(va[q].z); p[3] = (short)f2b(va[q].w);                 \
      *(bf4*)&As[BUF][row * 32 + slot * 8 + (j4 & 1) * 4] = p;                \
    }                                                                         \
  }
// one K-step: pack B(s) (freeing its buffer), refill buffer with B(s+2),
// prefetch A(s+1), MFMA(s), stage A(s+1) to LDS, barrier.
#define G1_STEP(S, XSCUR, CUR)                                                \
  {                                                                           \
    bf8 bfr;                                                                  \
    _Pragma("unroll")                                                         \
    for (int j = 0; j < 8; ++j) bfr[j] = (short)f2b(XSCUR[j]);                \
    if ((S) + 2 < NS) G1_GLOADB(((S) + 2) * 32, XSCUR);                       \
    if ((S) + 1 < NS) G1_GLOADA(((S) + 1) * 32);                              \
    _Pragma("unroll")                                                         \
    for (int mi = 0; mi < 8; ++mi) {                                          \
      bf8 afr = *(const bf8*)&As[CUR][(mi * 16 + l15) * 32 + (l4 ^ fA) * 8];  \
      acc[mi] = __builtin_amdgcn_mfma_f32_16x16x32_bf16(afr, bfr, acc[mi], 0, 0, 0); \
    }                                                                         \
    if ((S) + 1 < NS) G1_LSTOREA(CUR ^ 1);                                    \
    __syncthreads();                                                          \
  }

  const int fA = (l15 >> 2) & 3;        // A-read swizzle term
  const int NS = C_ / 32;               // 48 K-steps

  G1_GLOADA(0);
  G1_GLOADB(0, xs0);
  G1_GLOADB(32, xs1);
  G1_LSTOREA(0);
  __syncthreads();

  for (int sp = 0; sp < NS / 2; ++sp) {
    G1_STEP(2 * sp,     xs0, 0);
    G1_STEP(2 * sp + 1, xs1, 1);
  }

  // epilogue: +hconst, relu, LN over 128 h (per t-col), tanh, bf16 store
  const int t = t0 + w * 16 + l15;
  float sum = 0.f, ssq = 0.f;
#pragma unroll
  for (int mi = 0; mi < 8; ++mi) {
    float4 h4 = *(const float4*)(hconst + b * H_ + mi * 16 + l4 * 4);
    const float* hp = (const float*)&h4;
#pragma unroll
    for (int reg = 0; reg < 4; ++reg) {
      float v = fmaxf(acc[mi][reg] + hp[reg], 0.f);
      acc[mi][reg] = v;
      sum += v;
      ssq += v * v;
    }
  }
  sum += __shfl_xor(sum, 16); sum += __shfl_xor(sum, 32);
  ssq += __shfl_xor(ssq, 16); ssq += __shfl_xor(ssq, 32);
  const float mean = sum * (1.f / 128.f);
  const float rstd = rsqrtf(ssq * (1.f / 128.f) - mean * mean + 1e-5f);
  if (t < T_) {
    unsigned short* dst = hlnT + ((size_t)b * T_ + t) * H_;
#pragma unroll
    for (int mi = 0; mi < 8; ++mi) {
      float4 g4 = *(const float4*)(g1 + mi * 16 + l4 * 4);
      float4 e4 = *(const float4*)(be1 + mi * 16 + l4 * 4);
      const float* gp = (const float*)&g4;
      const float* ep = (const float*)&e4;
      bf4 p;
#pragma unroll
      for (int reg = 0; reg < 4; ++reg) {
        float o = tanhf((acc[mi][reg] - mean) * rstd * gp[reg] + ep[reg]);
        p[reg] = (short)f2b(o);
      }
      *(bf4*)&dst[mi * 16 + l4 * 4] = p;
    }
  }
}

// ---------------- K4: MFMA GEMM2 (alpha=w2@hln) + FIXED-MAX softmax + pooling -
// R18 structure (XCD swizzle, reg-A, exp2) + DEFERRED x/mask loads: chunk
// ch+1's mk/xv are loaded AFTER chunk ch's epilogue (same registers, freed
// by the epilogue) -- cover grows from ~MFMA-only to HSTORE+barrier+HLOAD+MFMA.
__global__ __launch_bounds__(256) void k_gemm2_pool(
    const float* __restrict__ x, const float* __restrict__ mask,
    const float* __restrict__ w2, const unsigned short* __restrict__ hlnT,
    const float* __restrict__ wl1,
    float* __restrict__ ps0, float* __restrict__ ps1, float* __restrict__ ps2) {
  __shared__ __align__(16) short Hs[2][64 * 128];   // [t][h] swizzled, 2x16KB
  // bijective XCD swizzle (1536 % 8 == 0)
  const int g = blockIdx.x;
  const int wid = (g & 7) * 192 + (g >> 3);   // 0..1535
  const int c0 = (wid % 24) * 64;
  const int rest = wid / 24;                  // 0..63
  const int b = rest & 15;
  const int part = rest >> 4;                 // 0..3
  const int tb = part * 512;
  const int te = min(tb + 512, T_);
  const int tid = threadIdx.x;
  const int lane = tid & 63;
  const int w = tid >> 6;
  const int l15 = lane & 15;
  const int l4 = lane >> 4;

  // A-frags in registers: af[ks] = bf16(log2e * w2[c0+w*16+l15][(ks*4+l4)*8..])
  bf8 af[4];
#pragma unroll
  for (int ks = 0; ks < 4; ++ks) {
    const float* src = w2 + (size_t)(c0 + w * 16 + l15) * H_ + (ks * 4 + l4) * 8;
    float4 v0 = *(const float4*)src;
    float4 v1 = *(const float4*)(src + 4);
    bf8 p;
    p[0] = (short)f2b(v0.x * LOG2E_); p[1] = (short)f2b(v0.y * LOG2E_);
    p[2] = (short)f2b(v0.z * LOG2E_); p[3] = (short)f2b(v0.w * LOG2E_);
    p[4] = (short)f2b(v1.x * LOG2E_); p[5] = (short)f2b(v1.y * LOG2E_);
    p[6] = (short)f2b(v1.z * LOG2E_); p[7] = (short)f2b(v1.w * LOG2E_);
    af[ks] = p;
  }

  // static per-row log2-domain logit bound Mc (exp2 arg <= ~0)
  float Mc[4];
  {
    float4 m4 = *(const float4*)(wl1 + c0 + w * 16 + l4 * 4);
    Mc[0] = m4.x; Mc[1] = m4.y; Mc[2] = m4.z; Mc[3] = m4.w;
  }

  // hoisted x row pointers for the pooling loads
  const float* xrowp[4];
#pragma unroll
  for (int reg = 0; reg < 4; ++reg)
    xrowp[reg] = x + ((size_t)(b * C_ + c0 + w * 16 + l4 * 4 + reg)) * T_;

  float s0[4], s1[4], s2[4];
#pragma unroll
  for (int r = 0; r < 4; ++r) { s0[r] = 0.f; s1[r] = 0.f; s2[r] = 0.f; }

  bf8 hreg[4];
  float mk[4];
  float xv[4][4];
#define G2_HLOAD(T0)                                                          \
  {                                                                           \
    _Pragma("unroll")                                                         \
    for (int q = 0; q < 4; ++q) {                                             \
      int idx = q * 256 + tid;                                                \
      int row = idx >> 4, slot = idx & 15;                                    \
      int t = (T0) + row;                                                     \
      if (t > T_ - 1) t = T_ - 1;                                             \
      hreg[q] = *(const bf8*)(hlnT + ((size_t)b * T_ + t) * H_ + slot * 8);   \
    }                                                                         \
  }
#define G2_HSTORE(BUF)                                                        \
  {                                                                           \
    _Pragma("unroll")                                                         \
    for (int q = 0; q < 4; ++q) {                                             \
      int idx = q * 256 + tid;                                                \
      int row = idx >> 4, slot = idx & 15;                                    \
      *(bf8*)&Hs[BUF][row * 128 + (slot ^ (row & 15)) * 8] = hreg[q];         \
    }                                                                         \
  }
// mask + x pooling loads for the chunk starting at T0 (fills mk/xv)
#define G2_XLOAD(T0)                                                          \
  {                                                                           \
    _Pragma("unroll")                                                         \
    for (int nj = 0; nj < 4; ++nj) {                                          \
      int t = (T0) + nj * 16 + l15;                                           \
      int tc = (t < T_) ? t : (T_ - 1);                                       \
      mk[nj] = (t < T_) ? mask[(size_t)b * T_ + t] : 0.f;                     \
      _Pragma("unroll")                                                       \
      for (int reg = 0; reg < 4; ++reg) xv[reg][nj] = xrowp[reg][tc];         \
    }                                                                         \
  }

  G2_HLOAD(tb);
  G2_HSTORE(0);
  G2_XLOAD(tb);          // chunk 0's mask/x, covered by the first barrier
  __syncthreads();

  const int NCH = (te - tb + 63) / 64;   // 8 for all parts
  for (int ch = 0; ch < NCH; ++ch) {
    const int t0 = tb + ch * 64;
    const int cur = ch & 1;
    if (ch + 1 < NCH) G2_HLOAD(t0 + 64);

    f4 acc[4];
#pragma unroll
    for (int nj = 0; nj < 4; ++nj) { f4 z = {0.f, 0.f, 0.f, 0.f}; acc[nj] = z; }

#pragma unroll
    for (int ks = 0; ks < 4; ++ks) {
      const int sw = (ks * 4 + l4) ^ l15;   // row&15 == l15 for B rows
      bf8 bb[4];
#pragma unroll
      for (int nj = 0; nj < 4; ++nj)
        bb[nj] = *(const bf8*)&Hs[cur][(nj * 16 + l15) * 128 + sw * 8];
#pragma unroll
      for (int nj = 0; nj < 4; ++nj)
        acc[nj] = __builtin_amdgcn_mfma_f32_16x16x32_bf16(af[ks], bb[nj], acc[nj], 0, 0, 0);
    }

    // epilogue: fixed-max exp2 + pooled partial sums (consumes mk/xv)
#pragma unroll
    for (int reg = 0; reg < 4; ++reg) {
      float a0 = s0[reg], a1 = s1[reg], a2 = s2[reg];
#pragma unroll
      for (int nj = 0; nj < 4; ++nj) {
        float e = (mk[nj] != 0.f) ? exp2f(acc[nj][reg] - Mc[reg]) : 0.f;
        float xvv = xv[reg][nj];
        a0 += e; a1 += e * xvv; a2 += e * xvv * xvv;
      }
      s0[reg] = a0; s1[reg] = a1; s2[reg] = a2;
    }

    // next chunk's mask/x loads AFTER the epilogue (regs freed above):
    // latency hides under HSTORE + barrier + next HLOAD + next MFMA.
    if (ch + 1 < NCH) {
      G2_XLOAD(t0 + 64);
      G2_HSTORE(cur ^ 1);
    }
    __syncthreads();
  }

  // merge the 16 lanes (t-cols) of each row group: plain adds
#pragma unroll
  for (int off = 1; off < 16; off <<= 1) {
#pragma unroll
    for (int r = 0; r < 4; ++r) {
      s0[r] += __shfl_xor(s0[r], off);
      s1[r] += __shfl_xor(s1[r], off);
      s2[r] += __shfl_xor(s2[r], off);
    }
  }
  if (l15 == 0) {
#pragma unroll
    for (int reg = 0; reg < 4; ++reg) {
      const int c = c0 + w * 16 + l4 * 4 + reg;
      const size_t j = ((size_t)(b * NT_ + part)) * C_ + c;
      ps0[j] = s0[reg]; ps1[j] = s1[reg]; ps2[j] = s2[reg];
    }
  }
}

// ---------------- K5: merge NT partials -> pooled stats -> final LN -> out ----
// one block per b; thread handles 6 c (c = i*256+tid); LN over 2C jointly.
__global__ __launch_bounds__(256) void k_pool_ln(
    const float* __restrict__ ps0, const float* __restrict__ ps1,
    const float* __restrict__ ps2, const float* __restrict__ g2,
    const float* __restrict__ be2, float* __restrict__ out) {
  __shared__ float rs[8];
  const int b = blockIdx.x;
  const int tid = threadIdx.x;
  const int lane = tid & 63;
  const int wave = tid >> 6;
  float mv[6], sv[6];
  float s = 0.f, q = 0.f;
#pragma unroll
  for (int i = 0; i < 6; ++i) {
    const int c = i * 256 + tid;
    float a0 = 0.f, a1 = 0.f, a2 = 0.f;
#pragma unroll
    for (int p = 0; p < NT_; ++p) {
      const size_t j = ((size_t)(b * NT_ + p)) * C_ + c;
      a0 += ps0[j]; a1 += ps1[j]; a2 += ps2[j];
    }
    float mean = a1 / a0;
    float var = a2 / a0 - mean * mean;
    float sd = sqrtf(fmaxf(var, 1e-5f));
    mv[i] = mean; sv[i] = sd;
    s += mean + sd;
    q += mean * mean + sd * sd;
  }
#pragma unroll
  for (int off = 32; off; off >>= 1) {
    s += __shfl_xor(s, off);
    q += __shfl_xor(q, off);
  }
  if (lane == 0) { rs[wave] = s; rs[4 + wave] = q; }
  __syncthreads();
  s = rs[0] + rs[1] + rs[2] + rs[3];
  q = rs[4] + rs[5] + rs[6] + rs[7];
  const float mu = s * (1.f / C2_);
  const float var = q * (1.f / C2_) - mu * mu;
  const float rstd = rsqrtf(var + 1e-5f);
#pragma unroll
  for (int i = 0; i < 6; ++i) {
    const int c = i * 256 + tid;
    out[b * C2_ + c]      = (mv[i] - mu) * rstd * g2[c] + be2[c];
    out[b * C2_ + C_ + c] = (sv[i] - mu) * rstd * g2[C_ + c] + be2[C_ + c];
  }
}

extern "C" void kernel_launch(void* const* d_in, const int* in_sizes, int n_in,
                              void* d_out, int out_size, void* d_ws, size_t ws_size,
                              hipStream_t stream) {
  const float* x    = (const float*)d_in[0];
  const float* mask = (const float*)d_in[1];
  const float* w1   = (const float*)d_in[2];
  const float* b1   = (const float*)d_in[3];
  const float* g1   = (const float*)d_in[4];
  const float* be1  = (const float*)d_in[5];
  const float* w2   = (const float*)d_in[6];
  // d_in[7] = b2: per-(b,c) constant on softmax logits -> softmax-invariant, dropped
  const float* g2   = (const float*)d_in[8];
  const float* be2  = (const float*)d_in[9];
  float* out = (float*)d_out;

  float* ws     = (float*)d_ws;
  float* mean0  = ws;                   // B*C
  float* std0   = mean0 + B_ * C_;      // B*C
  float* hconst = std0 + B_ * C_;       // B*H
  float* wl1    = hconst + B_ * H_;     // C
  float* ps0    = wl1 + C_;             // B*NT*C each:
  float* ps1    = ps0 + B_ * NT_ * C_;
  float* ps2    = ps1 + B_ * NT_ * C_;
  unsigned short* hlnT = (unsigned short*)(ps2 + B_ * NT_ * C_);  // B*T*H bf16

  k_stats<<<dim3(B_ * C_ / 4), dim3(256), 0, stream>>>(x, mask, mean0, std0);
  k_hconst_wl1<<<dim3(B_ * H_ / 4 + C_ / 4), dim3(256), 0, stream>>>(
      w1, b1, mean0, std0, w2, hconst, wl1);
  k_gemm1_ln<<<dim3((T_ + 63) / 64, B_), dim3(256), 0, stream>>>(x, w1, hconst, g1, be1, hlnT);
  k_gemm2_pool<<<dim3(24 * B_ * NT_), dim3(256), 0, stream>>>(x, mask, w2, hlnT, wl1,
                                                              ps0, ps1, ps2);
  k_pool_ln<<<dim3(B_), dim3(256), 0, stream>>>(ps0, ps1, ps2, g2, be2, out);
}